// Round 2
// baseline (441.618 us; speedup 1.0000x reference)
//
#include <hip/hip_runtime.h>
#include <cstdint>

#define NB 64
#define NN 16384
#define DWHERE 4
#define DWHAT 64
#define MAXOBJ 512
#define NEGADD 1638                 // int(0.1 * 16384)
#define KSEL (MAXOBJ + NEGADD)      // 2150
#define EPSV 0.001f

// in-place inclusive Hillis-Steele scan over buf[0..1023]; call with buf[t] set
// and a __syncthreads() already executed after the writes.
__device__ __forceinline__ void scan1024(int* buf, int t) {
  #pragma unroll
  for (int off = 1; off < 1024; off <<= 1) {
    int x = (t >= off) ? buf[t - off] : 0;
    __syncthreads();
    buf[t] += x;
    __syncthreads();
  }
}

// One block per batch. Computes, for each batch, the K=2150 selected source
// indices (ascending) and their "modified" value (1.0 keep / -1.0 negative /
// 0.0 fill) into workspace.
//
// Selection semantics (must match JAX stable argsort exactly):
//  - present = p > 0.5 ; keep = top-512 present by p, ties broken by LOWER index
//  - zero = !keep ; negative = last NEGADD zeros in index order
//  - selected = keep | negative, emitted in ascending index order
__global__ __launch_bounds__(1024) void select_kernel(
    const float* __restrict__ z_present,
    int* __restrict__ ws_idx,
    float* __restrict__ ws_mod)
{
  const int b = blockIdx.x;
  const int t = threadIdx.x;

  __shared__ int hist[4096];
  __shared__ int buf[1024];
  __shared__ int s_B1, s_above1, s_T, s_kTie;

  if (t == 0) { s_B1 = -1; s_above1 = 0; s_T = 0; s_kTie = 0; }

  // Load this thread's 16 contiguous p values once; key = float bits if
  // present else 0. All present values are in (0.5,1) -> exponent 126, so the
  // full 32-bit pattern is monotone in value; bits span 0x3F000000..0x3F7FFFFF.
  unsigned int key[16];
  {
    const float4* p4 = (const float4*)(z_present + (size_t)b * NN);
    #pragma unroll
    for (int j = 0; j < 4; ++j) {
      float4 v = p4[t * 4 + j];
      key[4 * j + 0] = (v.x > 0.5f) ? __float_as_uint(v.x) : 0u;
      key[4 * j + 1] = (v.y > 0.5f) ? __float_as_uint(v.y) : 0u;
      key[4 * j + 2] = (v.z > 0.5f) ? __float_as_uint(v.z) : 0u;
      key[4 * j + 3] = (v.w > 0.5f) ? __float_as_uint(v.w) : 0u;
    }
  }

  // ---- pass 1: histogram over top 11 mantissa bits (2048 buckets) ----
  #pragma unroll
  for (int j = 0; j < 4; ++j) hist[t + 1024 * j] = 0;
  __syncthreads();
  #pragma unroll
  for (int j = 0; j < 16; ++j)
    if (key[j]) atomicAdd(&hist[(key[j] >> 12) - 0x3F000u], 1);
  __syncthreads();

  // suffix sums via pair-sum + reversed inclusive scan
  int h0 = hist[2 * t], h1 = hist[2 * t + 1];
  buf[1023 - t] = h0 + h1;
  __syncthreads();
  scan1024(buf, t);
  int sufP  = buf[1023 - t];                    // suf over buckets >= 2t
  int sufPn = (t == 1023) ? 0 : buf[1022 - t];  // suf over buckets >= 2t+2
  int presentCount = buf[1023];
  if (presentCount > MAXOBJ) {
    int sufE = sufP;        // count(bucket >= 2t)
    int sufO = sufP - h0;   // count(bucket >= 2t+1)
    if (sufE >= MAXOBJ && sufO  < MAXOBJ) { s_B1 = 2 * t;     s_above1 = sufO;  }
    if (sufO >= MAXOBJ && sufPn < MAXOBJ) { s_B1 = 2 * t + 1; s_above1 = sufPn; }
  }
  __syncthreads();

  // ---- pass 2: refine within bucket B1 over low 12 mantissa bits ----
  int B1 = s_B1;
  if (B1 >= 0) {
    unsigned int hi = (unsigned int)B1 + 0x3F000u;
    #pragma unroll
    for (int j = 0; j < 4; ++j) hist[t + 1024 * j] = 0;
    __syncthreads();
    #pragma unroll
    for (int j = 0; j < 16; ++j)
      if (key[j] && ((key[j] >> 12) == hi)) atomicAdd(&hist[key[j] & 0xFFFu], 1);
    __syncthreads();
    int g0 = hist[4 * t], g1 = hist[4 * t + 1], g2 = hist[4 * t + 2], g3 = hist[4 * t + 3];
    buf[1023 - t] = g0 + g1 + g2 + g3;
    __syncthreads();
    scan1024(buf, t);
    int sufQ  = buf[1023 - t];
    int sufQn = (t == 1023) ? 0 : buf[1022 - t];
    int rem = MAXOBJ - s_above1;   // >= 1
    int s0 = sufQ;
    int s1 = s0 - g0;
    int s2 = s1 - g1;
    int s3 = s2 - g2;
    int s4 = sufQn;
    unsigned int baseT = hi << 12;
    if (s0 >= rem && s1 < rem) { s_T = (int)(baseT | (4u * t + 0)); s_kTie = rem - s1; }
    if (s1 >= rem && s2 < rem) { s_T = (int)(baseT | (4u * t + 1)); s_kTie = rem - s2; }
    if (s2 >= rem && s3 < rem) { s_T = (int)(baseT | (4u * t + 2)); s_kTie = rem - s3; }
    if (s3 >= rem && s4 < rem) { s_T = (int)(baseT | (4u * t + 3)); s_kTie = rem - s4; }
  }
  __syncthreads();

  const unsigned int T = (unsigned int)s_T;  // 0 => keep all present
  const int kTie = s_kTie;                   // # of T-valued elems to keep (lowest index first)

  // ---- pass 3: global rank of T-valued elements (for exact tie-break) ----
  int tieCnt = 0;
  if (T) {
    #pragma unroll
    for (int j = 0; j < 16; ++j) tieCnt += (key[j] == T) ? 1 : 0;
  }
  __syncthreads();
  buf[t] = tieCnt;
  __syncthreads();
  scan1024(buf, t);
  int tieBase = buf[t] - tieCnt;

  // ---- pass 4: keep flags + zero counts ----
  int keepMask = 0, zc = 0;
  {
    int tr = tieBase;
    #pragma unroll
    for (int j = 0; j < 16; ++j) {
      unsigned int kk = key[j];
      bool kp;
      if (kk > T) kp = true;
      else if (T && kk == T) { kp = (tr < kTie); tr++; }
      else kp = false;
      keepMask |= ((int)kp) << j;
      zc += kp ? 0 : 1;
    }
  }
  __syncthreads();
  buf[t] = zc;
  __syncthreads();
  scan1024(buf, t);
  int zBase = buf[t] - zc;   // zeros strictly before this thread's chunk
  int Z = buf[1023];         // total zeros

  // ---- pass 5: closed-form output slots, emit ----
  int thr = Z - NEGADD; if (thr < 0) thr = 0;   // zeros with 1-based rank > thr are negative
  int keepTotal = NN - Z;
  int KselTot = keepTotal + (Z - thr);          // total selected (== KSEL in practice)
  size_t obase = (size_t)b * KSEL;
  int ze = zBase;
  #pragma unroll
  for (int j = 0; j < 16; ++j) {
    int i = t * 16 + j;
    bool kp = (keepMask >> j) & 1;
    int keepBefore = i - ze;
    int negBefore = ze - thr; if (negBefore < 0) negBefore = 0;
    int selBefore = keepBefore + negBefore;
    if (kp) {
      ws_idx[obase + selBefore] = i;
      ws_mod[obase + selBefore] = 1.0f;
    } else {
      if (ze >= thr) {  // 1-based zero rank (ze+1) > thr  -> negative
        ws_idx[obase + selBefore] = i;
        ws_mod[obase + selBefore] = -1.0f;
      } else if (KselTot < KSEL) {
        // degenerate fallback: reference pads idx with non-selected indices
        int slot2 = KselTot + (i - selBefore);
        if (slot2 < KSEL) { ws_idx[obase + slot2] = i; ws_mod[obase + slot2] = 0.0f; }
      }
      ze++;
    }
  }
}

// 16 lanes per output row; gathers all four outputs.
__global__ __launch_bounds__(256) void gather_kernel(
    const float* __restrict__ z_where,
    const float* __restrict__ z_present,
    const float* __restrict__ z_what,
    const float* __restrict__ z_depth,
    const int* __restrict__ ws_idx,
    const float* __restrict__ ws_mod,
    float* __restrict__ out)
{
  int b = blockIdx.y;
  int tid = blockIdx.x * 256 + threadIdx.x;
  int k = tid >> 4;
  int l = tid & 15;
  if (k >= KSEL) return;
  int r = b * KSEL + k;
  int src = ws_idx[r];
  size_t gsrc = (size_t)b * NN + (unsigned)src;
  float p = z_present[gsrc];
  bool m = p > EPSV;   // mask for what/depth (EPS, not 0.5!)

  float4 v = ((const float4*)(z_what + gsrc * DWHAT))[l];
  if (!m) { v.x = 0.f; v.y = 0.f; v.z = 0.f; v.w = 0.f; }
  float* out2 = out + (size_t)NB * KSEL * (DWHERE + 1);
  ((float4*)(out2 + (size_t)r * DWHAT))[l] = v;

  if (l == 0) {
    ((float4*)out)[r] = ((const float4*)z_where)[gsrc];                       // out0: where (unmasked)
    out[(size_t)NB * KSEL * DWHERE + r] = ws_mod[r];                          // out1: modified
    out[(size_t)NB * KSEL * (DWHERE + 1 + DWHAT) + r] = m ? z_depth[gsrc] : 0.f; // out3: depth (masked)
  }
}

extern "C" void kernel_launch(void* const* d_in, const int* in_sizes, int n_in,
                              void* d_out, int out_size, void* d_ws, size_t ws_size,
                              hipStream_t stream) {
  const float* z_where   = (const float*)d_in[0];
  const float* z_present = (const float*)d_in[1];
  const float* z_what    = (const float*)d_in[2];
  // d_in[3] (z_what_scale) and d_in[5] (z_depth_scale) never affect outputs
  const float* z_depth   = (const float*)d_in[4];

  int*   ws_idx = (int*)d_ws;
  float* ws_mod = (float*)((char*)d_ws + (size_t)NB * KSEL * sizeof(int));

  select_kernel<<<NB, 1024, 0, stream>>>(z_present, ws_idx, ws_mod);

  dim3 grid((KSEL * 16 + 255) / 256, NB);  // 135 x 64 blocks
  gather_kernel<<<grid, 256, 0, stream>>>(z_where, z_present, z_what, z_depth,
                                          ws_idx, ws_mod, (float*)d_out);
}